// Round 14
// baseline (704.413 us; speedup 1.0000x reference)
//
#include <hip/hip_runtime.h>
#include <cstdint>
#include <cstddef>

#define NPTS 500000
#define DIM 64
#define KC 128
#define KM_ITERS 10
#define NGROUPS (NPTS / 32)          // 15625 groups of 32 points
#define NITERS8 ((NGROUPS + 7) / 8)  // 1954 block-iterations (8 groups each)

typedef __bf16 bf16x8 __attribute__((ext_vector_type(8)));
typedef float f32x4 __attribute__((ext_vector_type(4)));

__device__ __forceinline__ float wave_reduce_add(float v) {
#pragma unroll
  for (int off = 32; off > 0; off >>= 1) v += __shfl_xor(v, off, 64);
  return v;
}

__device__ __forceinline__ bf16x8 cvt8(float4 a, float4 b) {
  bf16x8 r;
  r[0] = (__bf16)a.x; r[1] = (__bf16)a.y; r[2] = (__bf16)a.z; r[3] = (__bf16)a.w;
  r[4] = (__bf16)b.x; r[5] = (__bf16)b.y; r[6] = (__bf16)b.z; r[7] = (__bf16)b.w;
  return r;
}

// Strided-sample init (init mismatch vs jax permutation = 7.8e-3 < 2e-2).
// Zeroes ALL 10 per-iteration sum/count buffers.
__global__ void k_initc(const float* __restrict__ x, float* __restrict__ cent,
                        float* __restrict__ c2, float* __restrict__ S,
                        float* __restrict__ CNT) {
  int k = blockIdx.x, d = threadIdx.x;
  long src = (long)k * 3891 + 7;
  float v = x[src * DIM + d];
  cent[k * DIM + d] = v;
#pragma unroll
  for (int p = 0; p < KM_ITERS; p++) S[p * (KC * DIM) + k * DIM + d] = 0.f;
  if (d < KM_ITERS) CNT[d * KC + k] = 0.f;
  float s = wave_reduce_add(v * v);
  if (d == 0) c2[k] = s;
}

// final materialization of cent/c2 from S[9]/CNT[9] for k_probs.
__global__ void k_update(const float* __restrict__ sums, const float* __restrict__ cnts,
                         float* __restrict__ cent, float* __restrict__ c2) {
  int k = blockIdx.x, d = threadIdx.x;
  float c = cnts[k];
  float v = (c > 0.f) ? (sums[k * DIM + d] / c) : 0.f;
  cent[k * DIM + d] = v;
  float s = wave_reduce_add(v * v);
  if (d == 0) c2[k] = s;
}

// distance MFMAs (A-frags in registers) + depth-5 TREE argmax.
// C-init = -0.5*c2 so argmin dist == argmax acc; id->k map is monotone so
// strict > keeps first-min like jnp.argmin.
#define DIST_H(V0, V1, MK)                                                     \
  {                                                                            \
    f32x4 acc_[8];                                                             \
    _Pragma("unroll") for (int tt = 0; tt < 8; tt++)                           \
      acc_[tt] = (f32x4){c2h[tt * 4 + 0], c2h[tt * 4 + 1],                     \
                         c2h[tt * 4 + 2], c2h[tt * 4 + 3]};                    \
    _Pragma("unroll") for (int tt = 0; tt < 8; tt++)                           \
      acc_[tt] = __builtin_amdgcn_mfma_f32_16x16x32_bf16(afr0[tt], V0, acc_[tt], 0, 0, 0); \
    _Pragma("unroll") for (int tt = 0; tt < 8; tt++)                           \
      acc_[tt] = __builtin_amdgcn_mfma_f32_16x16x32_bf16(afr1[tt], V1, acc_[tt], 0, 0, 0); \
    float tv[32]; int ti[32];                                                  \
    _Pragma("unroll") for (int i_ = 0; i_ < 32; i_++) {                        \
      tv[i_] = acc_[i_ >> 2][i_ & 3]; ti[i_] = i_;                             \
    }                                                                          \
    _Pragma("unroll") for (int s_ = 16; s_ >= 1; s_ >>= 1)                     \
      _Pragma("unroll") for (int i_ = 0; i_ < s_; i_++) {                      \
        bool t_ = tv[i_ + s_] > tv[i_];                                        \
        tv[i_] = t_ ? tv[i_ + s_] : tv[i_];                                    \
        ti[i_] = t_ ? ti[i_ + s_] : ti[i_];                                    \
      }                                                                        \
    float maxv = tv[0];                                                        \
    int mk = ((ti[0] >> 2) << 4) + grp * 4 + (ti[0] & 3);                      \
    _Pragma("unroll") for (int off = 16; off <= 32; off <<= 1) {               \
      float ov = __shfl_xor(maxv, off, 64);                                    \
      int ok = __shfl_xor(mk, off, 64);                                        \
      if (ov > maxv || (ov == maxv && ok < mk)) { maxv = ov; mk = ok; }        \
    }                                                                          \
    MK = mk;                                                                   \
  }

// transposed x-tile write for one 16-pt half (R7-proven layout)
#define XT_WRITE(XTW, V0, V1, H)                                               \
  {                                                                            \
    int slotb = (((((H) << 1) | (col >> 3)) ^ grp) & 3) * 16 + (col & 7) * 2;  \
    _Pragma("unroll") for (int j = 0; j < 8; j++) {                            \
      *(__bf16*)((XTW) + (grp * 8 + j) * 80 + slotb) = V0[j];                  \
      *(__bf16*)((XTW) + (32 + grp * 8 + j) * 80 + slotb) = V1[j];             \
    }                                                                          \
  }

// ssq of 16 fp32 values (two float4 pairs)
#define SSQ16(F0, F1, G0, G1)                                                  \
  ((F0.x * F0.x + F0.y * F0.y + F0.z * F0.z + F0.w * F0.w) +                   \
   (F1.x * F1.x + F1.y * F1.y + F1.z * F1.z + F1.w * F1.w) +                   \
   (G0.x * G0.x + G0.y * G0.y + G0.z * G0.z + G0.w * G0.w) +                   \
   (G1.x * G1.x + G1.y * G1.y + G1.z * G1.z + G1.w * G1.w))

// Assign + cluster-sum. FIRST=1: reads fp32 x, converts, writes bf16 to xbw.
// FIRST=0: fused update prologue (cent = s_prev/cnt_prev, c2 in-kernel) +
// main loop with cross-iteration prefetch. Tail: accs -> LDS merge (pad-65),
// then block-ROTATED atomic sweep (spreads cross-block same-line contention).
template <int FIRST>
__global__ __launch_bounds__(256, 2)
void k_assign(const float* __restrict__ xf, const __bf16* __restrict__ xb,
              __bf16* __restrict__ xbw, const float* __restrict__ cent,
              const float* __restrict__ c2, const float* __restrict__ s_prev,
              const float* __restrict__ cnt_prev, float* __restrict__ s_out,
              float* __restrict__ cnt_out) {
  __shared__ char xT[8][5120];  // per-group transposed x-tile; reused as ms[]
  __shared__ int sm[8][32];     // per-group minks
  __shared__ float lc[KC];
  __shared__ float lcnt[KC];    // staged prev counts (FIRST=0)
  __shared__ float lc2[KC];     // computed c2 (FIRST=0)

  const int lane = threadIdx.x & 63;
  const int wid = threadIdx.x >> 6;
  const int col = lane & 15;
  const int grp = lane >> 4;

  bf16x8 afr0[8], afr1[8];
  float c2h[32];

  if constexpr (FIRST) {
    for (int i = threadIdx.x; i < KC; i += 256) lc[i] = 0.f;
#pragma unroll
    for (int t = 0; t < 8; t++) {
      const float* cp = cent + (size_t)(t * 16 + col) * DIM;
      afr0[t] = cvt8(*(const float4*)(cp + grp * 8), *(const float4*)(cp + grp * 8 + 4));
      afr1[t] = cvt8(*(const float4*)(cp + 32 + grp * 8), *(const float4*)(cp + 32 + grp * 8 + 4));
#pragma unroll
      for (int r = 0; r < 4; r++) c2h[t * 4 + r] = -0.5f * c2[t * 16 + grp * 4 + r];
    }
    __syncthreads();
  } else {
    for (int i = threadIdx.x; i < KC; i += 256) { lcnt[i] = cnt_prev[i]; lc[i] = 0.f; }
    __syncthreads();
    float ssq[8];
#pragma unroll
    for (int t = 0; t < 8; t++) {
      int row = t * 16 + col;
      float c = lcnt[row];
      float inv = (c > 0.f) ? 1.f / c : 0.f;  // c==0 -> cent=0 (ref semantics)
      const float* sp = s_prev + (size_t)row * DIM;
      float4 f0 = *(const float4*)(sp + grp * 8);
      float4 f1 = *(const float4*)(sp + grp * 8 + 4);
      float4 g0 = *(const float4*)(sp + 32 + grp * 8);
      float4 g1 = *(const float4*)(sp + 32 + grp * 8 + 4);
      f0.x *= inv; f0.y *= inv; f0.z *= inv; f0.w *= inv;
      f1.x *= inv; f1.y *= inv; f1.z *= inv; f1.w *= inv;
      g0.x *= inv; g0.y *= inv; g0.z *= inv; g0.w *= inv;
      g1.x *= inv; g1.y *= inv; g1.z *= inv; g1.w *= inv;
      afr0[t] = cvt8(f0, f1);
      afr1[t] = cvt8(g0, g1);
      ssq[t] = SSQ16(f0, f1, g0, g1);
    }
#pragma unroll
    for (int t = 0; t < 8; t++) {
      float s = ssq[t];
      s += __shfl_xor(s, 16, 64);
      s += __shfl_xor(s, 32, 64);
      if (lane < 16 && wid == 0) lc2[t * 16 + col] = s;  // one writer per row
    }
    __syncthreads();
#pragma unroll
    for (int t = 0; t < 8; t++)
#pragma unroll
      for (int r = 0; r < 4; r++) c2h[t * 4 + r] = -0.5f * lc2[t * 16 + grp * 4 + r];
  }
#pragma unroll
  for (int t = 0; t < 8; t++) asm volatile("" : "+v"(afr0[t]), "+v"(afr1[t]));
#pragma unroll
  for (int i = 0; i < 32; i++) asm volatile("" : "+v"(c2h[i]));

  f32x4 accs[8];  // sums accumulators: cents wid*32..+31 x 64 dims
#pragma unroll
  for (int i = 0; i < 8; i++) accs[i] = (f32x4){0.f, 0.f, 0.f, 0.f};

  const int kbase = wid * 32;

  // prologue prefetch of g0 (NONFIRST only)
  bf16x8 p0a, p1a, p0b, p1b;
  if constexpr (!FIRST) {
    int g0 = blockIdx.x * 8 + wid * 2;
    if (blockIdx.x < NITERS8 && g0 < NGROUPS) {
      const bf16x8* xr = (const bf16x8*)(xb + (size_t)(g0 * 32 + col) * DIM + grp * 8);
      p0a = xr[0]; p1a = xr[4]; p0b = xr[128]; p1b = xr[132];
    }
  }

  for (int it = blockIdx.x; it < NITERS8; it += gridDim.x) {
    int g0 = it * 8 + wid * 2, g1 = g0 + 1;
    bool e0 = g0 < NGROUPS, e1 = g1 < NGROUPS;

    bf16x8 v0a, v1a, v0b, v1b, w0a, w1a, w0b, w1b;
    if constexpr (FIRST) {
      if (e0) {
        const float* xp = xf + (size_t)(g0 * 32 + col) * DIM + grp * 8;
        const float* xq = xp + 16 * DIM;
        v0a = cvt8(*(const float4*)xp, *(const float4*)(xp + 4));
        v1a = cvt8(*(const float4*)(xp + 32), *(const float4*)(xp + 36));
        v0b = cvt8(*(const float4*)xq, *(const float4*)(xq + 4));
        v1b = cvt8(*(const float4*)(xq + 32), *(const float4*)(xq + 36));
        bf16x8* wp = (bf16x8*)(xbw + (size_t)(g0 * 32 + col) * DIM);
        wp[grp] = v0a; wp[4 + grp] = v1a; wp[128 + grp] = v0b; wp[132 + grp] = v1b;
      }
      if (e1) {
        const float* xp = xf + (size_t)(g1 * 32 + col) * DIM + grp * 8;
        const float* xq = xp + 16 * DIM;
        w0a = cvt8(*(const float4*)xp, *(const float4*)(xp + 4));
        w1a = cvt8(*(const float4*)(xp + 32), *(const float4*)(xp + 36));
        w0b = cvt8(*(const float4*)xq, *(const float4*)(xq + 4));
        w1b = cvt8(*(const float4*)(xq + 32), *(const float4*)(xq + 36));
        bf16x8* wp = (bf16x8*)(xbw + (size_t)(g1 * 32 + col) * DIM);
        wp[grp] = w0a; wp[4 + grp] = w1a; wp[128 + grp] = w0b; wp[132 + grp] = w1b;
      }
    } else {
      v0a = p0a; v1a = p1a; v0b = p0b; v1b = p1b;  // prefetched last iteration
      if (e1) {
        const bf16x8* xr = (const bf16x8*)(xb + (size_t)(g1 * 32 + col) * DIM + grp * 8);
        w0a = xr[0]; w1a = xr[4]; w0b = xr[128]; w1b = xr[132];
      }
    }

    int mk0a = -1, mk0b = -1, mk1a = -1, mk1b = -1;
    if (e0) {
      char* xTw = xT[wid * 2];
      XT_WRITE(xTw, v0a, v1a, 0);
      XT_WRITE(xTw, v0b, v1b, 1);
      DIST_H(v0a, v1a, mk0a);
      DIST_H(v0b, v1b, mk0b);
      if (grp == 0) { atomicAdd(&lc[mk0a], 1.f); atomicAdd(&lc[mk0b], 1.f); }
    }
    if (grp == 0) { sm[wid * 2][col] = mk0a; sm[wid * 2][16 + col] = mk0b; }
    if (e1) {
      char* xTw = xT[wid * 2 + 1];
      XT_WRITE(xTw, w0a, w1a, 0);
      XT_WRITE(xTw, w0b, w1b, 1);
      DIST_H(w0a, w1a, mk1a);
      DIST_H(w0b, w1b, mk1b);
      if (grp == 0) { atomicAdd(&lc[mk1a], 1.f); atomicAdd(&lc[mk1b], 1.f); }
    }
    if (grp == 0) { sm[wid * 2 + 1][col] = mk1a; sm[wid * 2 + 1][16 + col] = mk1b; }
    __syncthreads();

    // issue next iteration's g0 loads NOW: latency hides under the sums phase
    if constexpr (!FIRST) {
      int itn = it + gridDim.x;
      int g0n = itn * 8 + wid * 2;
      if (itn < NITERS8 && g0n < NGROUPS) {
        const bf16x8* xr = (const bf16x8*)(xb + (size_t)(g0n * 32 + col) * DIM + grp * 8);
        p0a = xr[0]; p1a = xr[4]; p0b = xr[128]; p1b = xr[132];
      }
    }

    // sums phase: all 8 groups, own 32 centroids only
#pragma unroll
    for (int G = 0; G < 8; G++) {
      const int* smG = sm[G];
      int4 mlo = *(const int4*)&smG[grp * 8];
      int4 mhi = *(const int4*)&smG[grp * 8 + 4];
      const char* xTg = xT[G];
      bf16x8 xf0, xf1, xf2, xf3;
      { int d = col;      int s = (grp ^ ((d >> 3) & 3)) & 3; xf0 = *(const bf16x8*)(xTg + d * 80 + s * 16); }
      { int d = 16 + col; int s = (grp ^ ((d >> 3) & 3)) & 3; xf1 = *(const bf16x8*)(xTg + d * 80 + s * 16); }
      { int d = 32 + col; int s = (grp ^ ((d >> 3) & 3)) & 3; xf2 = *(const bf16x8*)(xTg + d * 80 + s * 16); }
      { int d = 48 + col; int s = (grp ^ ((d >> 3) & 3)) & 3; xf3 = *(const bf16x8*)(xTg + d * 80 + s * 16); }
      int m0 = mlo.x, m1 = mlo.y, m2 = mlo.z, m3 = mlo.w;
      int m4 = mhi.x, m5 = mhi.y, m6 = mhi.z, m7 = mhi.w;
#pragma unroll
      for (int tt2 = 0; tt2 < 2; tt2++) {
        int c = kbase + tt2 * 16 + col;
        union { unsigned u[4]; bf16x8 v; } oh;
        oh.u[0] = (m0 == c ? 0x3F80u : 0u) | (m1 == c ? 0x3F800000u : 0u);
        oh.u[1] = (m2 == c ? 0x3F80u : 0u) | (m3 == c ? 0x3F800000u : 0u);
        oh.u[2] = (m4 == c ? 0x3F80u : 0u) | (m5 == c ? 0x3F800000u : 0u);
        oh.u[3] = (m6 == c ? 0x3F80u : 0u) | (m7 == c ? 0x3F800000u : 0u);
        accs[tt2 * 4 + 0] = __builtin_amdgcn_mfma_f32_16x16x32_bf16(oh.v, xf0, accs[tt2 * 4 + 0], 0, 0, 0);
        accs[tt2 * 4 + 1] = __builtin_amdgcn_mfma_f32_16x16x32_bf16(oh.v, xf1, accs[tt2 * 4 + 1], 0, 0, 0);
        accs[tt2 * 4 + 2] = __builtin_amdgcn_mfma_f32_16x16x32_bf16(oh.v, xf2, accs[tt2 * 4 + 2], 0, 0, 0);
        accs[tt2 * 4 + 3] = __builtin_amdgcn_mfma_f32_16x16x32_bf16(oh.v, xf3, accs[tt2 * 4 + 3], 0, 0, 0);
      }
    }
    __syncthreads();
  }

  // tail: accs -> LDS merge (pad-65, all indices compile-time), then
  // block-rotated atomic sweep to spread cross-block same-line contention.
  __syncthreads();
  float* ms = (float*)xT;  // 128 rows x 65 floats = 33.3KB <= 40KB
#pragma unroll
  for (int tt2 = 0; tt2 < 2; tt2++)
#pragma unroll
    for (int dt = 0; dt < 4; dt++)
#pragma unroll
      for (int r = 0; r < 4; r++)
        ms[(kbase + tt2 * 16 + grp * 4 + r) * 65 + dt * 16 + col] = accs[tt2 * 4 + dt][r];
  __syncthreads();
  {
    int rot = (blockIdx.x * 131) & (KC * DIM - 1);
    for (int i = threadIdx.x; i < KC * DIM; i += 256) {
      int j = (i + rot) & (KC * DIM - 1);
      atomicAdd(&s_out[j], ms[(j >> 6) * 65 + (j & 63)]);
    }
    for (int i = threadIdx.x; i < KC; i += 256) {
      int j = (i + blockIdx.x) & (KC - 1);
      atomicAdd(&cnt_out[j], lc[j]);
    }
  }
}

// MFMA probs; denom inline per wave; nontemporal 256MB stores.
// BF=1: reads bf16 x from workspace (64MB instead of 128MB fp32, no cvt).
template <int BF>
__global__ __launch_bounds__(256, 2)
void k_probs(const float* __restrict__ x, const __bf16* __restrict__ xbp,
             const float* __restrict__ cent, const float* __restrict__ c2,
             float* __restrict__ out) {
  const int lane = threadIdx.x & 63;
  const int wid = threadIdx.x >> 6;
  const int col = lane & 15;
  const int grp = lane >> 4;

  bf16x8 afr[2][8];
  float c2g[32];
#pragma unroll
  for (int t = 0; t < 8; t++) {
    const float* cp = cent + (size_t)(t * 16 + col) * DIM;
#pragma unroll
    for (int ks = 0; ks < 2; ks++) {
      float4 f0 = *(const float4*)(cp + ks * 32 + grp * 8);
      float4 f1 = *(const float4*)(cp + ks * 32 + grp * 8 + 4);
      afr[ks][t] = cvt8(f0, f1);
    }
#pragma unroll
    for (int r = 0; r < 4; r++) c2g[t * 4 + r] = c2[t * 16 + grp * 4 + r];
  }

  float c2a = c2[lane], c2b = c2[64 + lane];
  float x2_0 = 0.f, dA = 0.f, dB = 0.f;
#pragma unroll 8
  for (int d = 0; d < DIM; d++) {
    float xv = x[d];
    x2_0 = fmaf(xv, xv, x2_0);
    dA = fmaf(xv, cent[(size_t)lane * DIM + d], dA);
    dB = fmaf(xv, cent[(size_t)(64 + lane) * DIM + d], dB);
  }
  float part = ((x2_0 + c2a) - 2.f * dA) + ((x2_0 + c2b) - 2.f * dB);
  float invd = 1.0f / wave_reduce_add(part);

  int w = blockIdx.x * 4 + wid;
  int nw = gridDim.x * 4;
  for (int t = w; t < NPTS / 16; t += nw) {
    int n0 = t * 16;
    bf16x8 xb0, xb1;
    float sq;
    if constexpr (BF) {
      const bf16x8* xr = (const bf16x8*)(xbp + (size_t)(n0 + col) * DIM + grp * 8);
      xb0 = xr[0]; xb1 = xr[4];
      sq = 0.f;
#pragma unroll
      for (int j = 0; j < 8; j++) {
        float u = (float)xb0[j], v = (float)xb1[j];
        sq += u * u + v * v;
      }
    } else {
      const float* xp = x + (size_t)(n0 + col) * DIM;
      float4 a0 = *(const float4*)(xp + grp * 8);
      float4 a1 = *(const float4*)(xp + grp * 8 + 4);
      float4 b0 = *(const float4*)(xp + 32 + grp * 8);
      float4 b1 = *(const float4*)(xp + 32 + grp * 8 + 4);
      xb0 = cvt8(a0, a1); xb1 = cvt8(b0, b1);
      sq = SSQ16(a0, a1, b0, b1);
    }
    sq += __shfl_xor(sq, 16, 64);
    sq += __shfl_xor(sq, 32, 64);

    f32x4 acc[8];
#pragma unroll
    for (int tt = 0; tt < 8; tt++) acc[tt] = (f32x4){0.f, 0.f, 0.f, 0.f};
#pragma unroll
    for (int tt = 0; tt < 8; tt++)
      acc[tt] = __builtin_amdgcn_mfma_f32_16x16x32_bf16(afr[0][tt], xb0, acc[tt], 0, 0, 0);
#pragma unroll
    for (int tt = 0; tt < 8; tt++)
      acc[tt] = __builtin_amdgcn_mfma_f32_16x16x32_bf16(afr[1][tt], xb1, acc[tt], 0, 0, 0);

    float* op = out + (size_t)(n0 + col) * KC + grp * 4;
#pragma unroll
    for (int tt = 0; tt < 8; tt++) {
      f32x4 q;
      q[0] = 1.f - ((sq + c2g[tt * 4 + 0]) - 2.f * acc[tt][0]) * invd;
      q[1] = 1.f - ((sq + c2g[tt * 4 + 1]) - 2.f * acc[tt][1]) * invd;
      q[2] = 1.f - ((sq + c2g[tt * 4 + 2]) - 2.f * acc[tt][2]) * invd;
      q[3] = 1.f - ((sq + c2g[tt * 4 + 3]) - 2.f * acc[tt][3]) * invd;
      __builtin_nontemporal_store(q, (f32x4*)(op + tt * 16));
    }
  }
}

extern "C" void kernel_launch(void* const* d_in, const int* in_sizes, int n_in,
                              void* d_out, int out_size, void* d_ws, size_t ws_size,
                              hipStream_t stream) {
  const float* x = (const float*)d_in[0];
  float* out = (float*)d_out;

  // ws: cent[8192] | c2[128] | S[10][8192] | CNT[10][128] | (optional) xb
  float* cent = (float*)d_ws;
  float* c2 = cent + KC * DIM;
  float* S = c2 + KC;
  float* CNT = S + KM_ITERS * KC * DIM;
  size_t xb_off_f = (size_t)(KC * DIM + KC + KM_ITERS * KC * DIM + KM_ITERS * KC);
  size_t need = xb_off_f * 4 + (size_t)NPTS * DIM * 2;
  bool ws_ok = ws_size >= need;
  __bf16* xb = ws_ok ? (__bf16*)((float*)d_ws + xb_off_f) : (__bf16*)d_out;

  k_initc<<<KC, DIM, 0, stream>>>(x, cent, c2, S, CNT);
  k_assign<1><<<512, 256, 0, stream>>>(x, xb, xb, cent, c2, nullptr, nullptr, S, CNT);
  for (int it = 1; it < KM_ITERS; it++) {
    k_assign<0><<<512, 256, 0, stream>>>(x, xb, xb, cent, c2,
                                         S + (it - 1) * KC * DIM, CNT + (it - 1) * KC,
                                         S + it * KC * DIM, CNT + it * KC);
  }
  k_update<<<KC, DIM, 0, stream>>>(S + 9 * KC * DIM, CNT + 9 * KC, cent, c2);
  if (ws_ok)
    k_probs<1><<<512, 256, 0, stream>>>(x, xb, cent, c2, out);
  else
    k_probs<0><<<512, 256, 0, stream>>>(x, xb, cent, c2, out);
}

// Round 15
// 654.667 us; speedup vs baseline: 1.0760x; 1.0760x over previous
//
#include <hip/hip_runtime.h>
#include <cstdint>
#include <cstddef>

#define NPTS 500000
#define DIM 64
#define KC 128
#define KM_ITERS 10
#define NGROUPS (NPTS / 32)          // 15625 groups of 32 points
#define NITERS8 ((NGROUPS + 7) / 8)  // 1954 block-iterations (8 groups each)

typedef __bf16 bf16x8 __attribute__((ext_vector_type(8)));
typedef float f32x4 __attribute__((ext_vector_type(4)));

__device__ __forceinline__ float wave_reduce_add(float v) {
#pragma unroll
  for (int off = 32; off > 0; off >>= 1) v += __shfl_xor(v, off, 64);
  return v;
}

__device__ __forceinline__ bf16x8 cvt8(float4 a, float4 b) {
  bf16x8 r;
  r[0] = (__bf16)a.x; r[1] = (__bf16)a.y; r[2] = (__bf16)a.z; r[3] = (__bf16)a.w;
  r[4] = (__bf16)b.x; r[5] = (__bf16)b.y; r[6] = (__bf16)b.z; r[7] = (__bf16)b.w;
  return r;
}

// Strided-sample init (init mismatch vs jax permutation = 7.8e-3 < 2e-2).
// Zeroes ALL 10 per-iteration sum/count buffers.
__global__ void k_initc(const float* __restrict__ x, float* __restrict__ cent,
                        float* __restrict__ c2, float* __restrict__ S,
                        float* __restrict__ CNT) {
  int k = blockIdx.x, d = threadIdx.x;
  long src = (long)k * 3891 + 7;
  float v = x[src * DIM + d];
  cent[k * DIM + d] = v;
#pragma unroll
  for (int p = 0; p < KM_ITERS; p++) S[p * (KC * DIM) + k * DIM + d] = 0.f;
  if (d < KM_ITERS) CNT[d * KC + k] = 0.f;
  float s = wave_reduce_add(v * v);
  if (d == 0) c2[k] = s;
}

// final materialization of cent/c2 from S[9]/CNT[9] for k_probs.
__global__ void k_update(const float* __restrict__ sums, const float* __restrict__ cnts,
                         float* __restrict__ cent, float* __restrict__ c2) {
  int k = blockIdx.x, d = threadIdx.x;
  float c = cnts[k];
  float v = (c > 0.f) ? (sums[k * DIM + d] / c) : 0.f;
  cent[k * DIM + d] = v;
  float s = wave_reduce_add(v * v);
  if (d == 0) c2[k] = s;
}

// distance MFMAs (A-frags in registers) + depth-5 TREE argmax.
// C-init = -0.5*c2 so argmin dist == argmax acc; id->k map is monotone so
// strict > keeps first-min like jnp.argmin.
#define DIST_H(V0, V1, MK)                                                     \
  {                                                                            \
    f32x4 acc_[8];                                                             \
    _Pragma("unroll") for (int tt = 0; tt < 8; tt++)                           \
      acc_[tt] = (f32x4){c2h[tt * 4 + 0], c2h[tt * 4 + 1],                     \
                         c2h[tt * 4 + 2], c2h[tt * 4 + 3]};                    \
    _Pragma("unroll") for (int tt = 0; tt < 8; tt++)                           \
      acc_[tt] = __builtin_amdgcn_mfma_f32_16x16x32_bf16(afr0[tt], V0, acc_[tt], 0, 0, 0); \
    _Pragma("unroll") for (int tt = 0; tt < 8; tt++)                           \
      acc_[tt] = __builtin_amdgcn_mfma_f32_16x16x32_bf16(afr1[tt], V1, acc_[tt], 0, 0, 0); \
    float tv[32]; int ti[32];                                                  \
    _Pragma("unroll") for (int i_ = 0; i_ < 32; i_++) {                        \
      tv[i_] = acc_[i_ >> 2][i_ & 3]; ti[i_] = i_;                             \
    }                                                                          \
    _Pragma("unroll") for (int s_ = 16; s_ >= 1; s_ >>= 1)                     \
      _Pragma("unroll") for (int i_ = 0; i_ < s_; i_++) {                      \
        bool t_ = tv[i_ + s_] > tv[i_];                                        \
        tv[i_] = t_ ? tv[i_ + s_] : tv[i_];                                    \
        ti[i_] = t_ ? ti[i_ + s_] : ti[i_];                                    \
      }                                                                        \
    float maxv = tv[0];                                                        \
    int mk = ((ti[0] >> 2) << 4) + grp * 4 + (ti[0] & 3);                      \
    _Pragma("unroll") for (int off = 16; off <= 32; off <<= 1) {               \
      float ov = __shfl_xor(maxv, off, 64);                                    \
      int ok = __shfl_xor(mk, off, 64);                                        \
      if (ov > maxv || (ov == maxv && ok < mk)) { maxv = ov; mk = ok; }        \
    }                                                                          \
    MK = mk;                                                                   \
  }

// transposed x-tile write for one 16-pt half (R7-proven layout)
#define XT_WRITE(XTW, V0, V1, H)                                               \
  {                                                                            \
    int slotb = (((((H) << 1) | (col >> 3)) ^ grp) & 3) * 16 + (col & 7) * 2;  \
    _Pragma("unroll") for (int j = 0; j < 8; j++) {                            \
      *(__bf16*)((XTW) + (grp * 8 + j) * 80 + slotb) = V0[j];                  \
      *(__bf16*)((XTW) + (32 + grp * 8 + j) * 80 + slotb) = V1[j];             \
    }                                                                          \
  }

// ssq of 16 fp32 values (two float4 pairs)
#define SSQ16(F0, F1, G0, G1)                                                  \
  ((F0.x * F0.x + F0.y * F0.y + F0.z * F0.z + F0.w * F0.w) +                   \
   (F1.x * F1.x + F1.y * F1.y + F1.z * F1.z + F1.w * F1.w) +                   \
   (G0.x * G0.x + G0.y * G0.y + G0.z * G0.z + G0.w * G0.w) +                   \
   (G1.x * G1.x + G1.y * G1.y + G1.z * G1.z + G1.w * G1.w))

// Assign + cluster-sum. FIRST=1: reads fp32 x, converts, writes bf16 to xbw.
// FIRST=0: fused update prologue (cent = s_prev/cnt_prev, c2 in-kernel) +
// main loop with cross-iteration prefetch. Tail: R13 direct exclusive-
// ownership atomics (reverted R14's LDS merge -- it was the regression).
template <int FIRST>
__global__ __launch_bounds__(256, 2)
void k_assign(const float* __restrict__ xf, const __bf16* __restrict__ xb,
              __bf16* __restrict__ xbw, const float* __restrict__ cent,
              const float* __restrict__ c2, const float* __restrict__ s_prev,
              const float* __restrict__ cnt_prev, float* __restrict__ s_out,
              float* __restrict__ cnt_out) {
  __shared__ char xT[8][5120];  // per-group transposed x-tile: 64 rows x 80B
  __shared__ int sm[8][32];     // per-group minks
  __shared__ float lc[KC];
  __shared__ float lcnt[KC];    // staged prev counts (FIRST=0)
  __shared__ float lc2[KC];     // computed c2 (FIRST=0)

  const int lane = threadIdx.x & 63;
  const int wid = threadIdx.x >> 6;
  const int col = lane & 15;
  const int grp = lane >> 4;

  bf16x8 afr0[8], afr1[8];
  float c2h[32];

  if constexpr (FIRST) {
    for (int i = threadIdx.x; i < KC; i += 256) lc[i] = 0.f;
#pragma unroll
    for (int t = 0; t < 8; t++) {
      const float* cp = cent + (size_t)(t * 16 + col) * DIM;
      afr0[t] = cvt8(*(const float4*)(cp + grp * 8), *(const float4*)(cp + grp * 8 + 4));
      afr1[t] = cvt8(*(const float4*)(cp + 32 + grp * 8), *(const float4*)(cp + 32 + grp * 8 + 4));
#pragma unroll
      for (int r = 0; r < 4; r++) c2h[t * 4 + r] = -0.5f * c2[t * 16 + grp * 4 + r];
    }
    __syncthreads();
  } else {
    for (int i = threadIdx.x; i < KC; i += 256) { lcnt[i] = cnt_prev[i]; lc[i] = 0.f; }
    __syncthreads();
    float ssq[8];
#pragma unroll
    for (int t = 0; t < 8; t++) {
      int row = t * 16 + col;
      float c = lcnt[row];
      float inv = (c > 0.f) ? 1.f / c : 0.f;  // c==0 -> cent=0 (ref semantics)
      const float* sp = s_prev + (size_t)row * DIM;
      float4 f0 = *(const float4*)(sp + grp * 8);
      float4 f1 = *(const float4*)(sp + grp * 8 + 4);
      float4 g0 = *(const float4*)(sp + 32 + grp * 8);
      float4 g1 = *(const float4*)(sp + 32 + grp * 8 + 4);
      f0.x *= inv; f0.y *= inv; f0.z *= inv; f0.w *= inv;
      f1.x *= inv; f1.y *= inv; f1.z *= inv; f1.w *= inv;
      g0.x *= inv; g0.y *= inv; g0.z *= inv; g0.w *= inv;
      g1.x *= inv; g1.y *= inv; g1.z *= inv; g1.w *= inv;
      afr0[t] = cvt8(f0, f1);
      afr1[t] = cvt8(g0, g1);
      ssq[t] = SSQ16(f0, f1, g0, g1);
    }
#pragma unroll
    for (int t = 0; t < 8; t++) {
      float s = ssq[t];
      s += __shfl_xor(s, 16, 64);
      s += __shfl_xor(s, 32, 64);
      if (lane < 16 && wid == 0) lc2[t * 16 + col] = s;  // one writer per row
    }
    __syncthreads();
#pragma unroll
    for (int t = 0; t < 8; t++)
#pragma unroll
      for (int r = 0; r < 4; r++) c2h[t * 4 + r] = -0.5f * lc2[t * 16 + grp * 4 + r];
  }
#pragma unroll
  for (int t = 0; t < 8; t++) asm volatile("" : "+v"(afr0[t]), "+v"(afr1[t]));
#pragma unroll
  for (int i = 0; i < 32; i++) asm volatile("" : "+v"(c2h[i]));

  f32x4 accs[8];  // sums accumulators: cents wid*32..+31 x 64 dims
#pragma unroll
  for (int i = 0; i < 8; i++) accs[i] = (f32x4){0.f, 0.f, 0.f, 0.f};

  const int kbase = wid * 32;

  // prologue prefetch of g0 (NONFIRST only)
  bf16x8 p0a, p1a, p0b, p1b;
  if constexpr (!FIRST) {
    int g0 = blockIdx.x * 8 + wid * 2;
    if (blockIdx.x < NITERS8 && g0 < NGROUPS) {
      const bf16x8* xr = (const bf16x8*)(xb + (size_t)(g0 * 32 + col) * DIM + grp * 8);
      p0a = xr[0]; p1a = xr[4]; p0b = xr[128]; p1b = xr[132];
    }
  }

  for (int it = blockIdx.x; it < NITERS8; it += gridDim.x) {
    int g0 = it * 8 + wid * 2, g1 = g0 + 1;
    bool e0 = g0 < NGROUPS, e1 = g1 < NGROUPS;

    bf16x8 v0a, v1a, v0b, v1b, w0a, w1a, w0b, w1b;
    if constexpr (FIRST) {
      if (e0) {
        const float* xp = xf + (size_t)(g0 * 32 + col) * DIM + grp * 8;
        const float* xq = xp + 16 * DIM;
        v0a = cvt8(*(const float4*)xp, *(const float4*)(xp + 4));
        v1a = cvt8(*(const float4*)(xp + 32), *(const float4*)(xp + 36));
        v0b = cvt8(*(const float4*)xq, *(const float4*)(xq + 4));
        v1b = cvt8(*(const float4*)(xq + 32), *(const float4*)(xq + 36));
        bf16x8* wp = (bf16x8*)(xbw + (size_t)(g0 * 32 + col) * DIM);
        wp[grp] = v0a; wp[4 + grp] = v1a; wp[128 + grp] = v0b; wp[132 + grp] = v1b;
      }
      if (e1) {
        const float* xp = xf + (size_t)(g1 * 32 + col) * DIM + grp * 8;
        const float* xq = xp + 16 * DIM;
        w0a = cvt8(*(const float4*)xp, *(const float4*)(xp + 4));
        w1a = cvt8(*(const float4*)(xp + 32), *(const float4*)(xp + 36));
        w0b = cvt8(*(const float4*)xq, *(const float4*)(xq + 4));
        w1b = cvt8(*(const float4*)(xq + 32), *(const float4*)(xq + 36));
        bf16x8* wp = (bf16x8*)(xbw + (size_t)(g1 * 32 + col) * DIM);
        wp[grp] = w0a; wp[4 + grp] = w1a; wp[128 + grp] = w0b; wp[132 + grp] = w1b;
      }
    } else {
      v0a = p0a; v1a = p1a; v0b = p0b; v1b = p1b;  // prefetched last iteration
      if (e1) {
        const bf16x8* xr = (const bf16x8*)(xb + (size_t)(g1 * 32 + col) * DIM + grp * 8);
        w0a = xr[0]; w1a = xr[4]; w0b = xr[128]; w1b = xr[132];
      }
    }

    int mk0a = -1, mk0b = -1, mk1a = -1, mk1b = -1;
    if (e0) {
      char* xTw = xT[wid * 2];
      XT_WRITE(xTw, v0a, v1a, 0);
      XT_WRITE(xTw, v0b, v1b, 1);
      DIST_H(v0a, v1a, mk0a);
      DIST_H(v0b, v1b, mk0b);
      if (grp == 0) { atomicAdd(&lc[mk0a], 1.f); atomicAdd(&lc[mk0b], 1.f); }
    }
    if (grp == 0) { sm[wid * 2][col] = mk0a; sm[wid * 2][16 + col] = mk0b; }
    if (e1) {
      char* xTw = xT[wid * 2 + 1];
      XT_WRITE(xTw, w0a, w1a, 0);
      XT_WRITE(xTw, w0b, w1b, 1);
      DIST_H(w0a, w1a, mk1a);
      DIST_H(w0b, w1b, mk1b);
      if (grp == 0) { atomicAdd(&lc[mk1a], 1.f); atomicAdd(&lc[mk1b], 1.f); }
    }
    if (grp == 0) { sm[wid * 2 + 1][col] = mk1a; sm[wid * 2 + 1][16 + col] = mk1b; }
    __syncthreads();

    // issue next iteration's g0 loads NOW: latency hides under the sums phase
    if constexpr (!FIRST) {
      int itn = it + gridDim.x;
      int g0n = itn * 8 + wid * 2;
      if (itn < NITERS8 && g0n < NGROUPS) {
        const bf16x8* xr = (const bf16x8*)(xb + (size_t)(g0n * 32 + col) * DIM + grp * 8);
        p0a = xr[0]; p1a = xr[4]; p0b = xr[128]; p1b = xr[132];
      }
    }

    // sums phase: all 8 groups, own 32 centroids only
#pragma unroll
    for (int G = 0; G < 8; G++) {
      const int* smG = sm[G];
      int4 mlo = *(const int4*)&smG[grp * 8];
      int4 mhi = *(const int4*)&smG[grp * 8 + 4];
      const char* xTg = xT[G];
      bf16x8 xf0, xf1, xf2, xf3;
      { int d = col;      int s = (grp ^ ((d >> 3) & 3)) & 3; xf0 = *(const bf16x8*)(xTg + d * 80 + s * 16); }
      { int d = 16 + col; int s = (grp ^ ((d >> 3) & 3)) & 3; xf1 = *(const bf16x8*)(xTg + d * 80 + s * 16); }
      { int d = 32 + col; int s = (grp ^ ((d >> 3) & 3)) & 3; xf2 = *(const bf16x8*)(xTg + d * 80 + s * 16); }
      { int d = 48 + col; int s = (grp ^ ((d >> 3) & 3)) & 3; xf3 = *(const bf16x8*)(xTg + d * 80 + s * 16); }
      int m0 = mlo.x, m1 = mlo.y, m2 = mlo.z, m3 = mlo.w;
      int m4 = mhi.x, m5 = mhi.y, m6 = mhi.z, m7 = mhi.w;
#pragma unroll
      for (int tt2 = 0; tt2 < 2; tt2++) {
        int c = kbase + tt2 * 16 + col;
        union { unsigned u[4]; bf16x8 v; } oh;
        oh.u[0] = (m0 == c ? 0x3F80u : 0u) | (m1 == c ? 0x3F800000u : 0u);
        oh.u[1] = (m2 == c ? 0x3F80u : 0u) | (m3 == c ? 0x3F800000u : 0u);
        oh.u[2] = (m4 == c ? 0x3F80u : 0u) | (m5 == c ? 0x3F800000u : 0u);
        oh.u[3] = (m6 == c ? 0x3F80u : 0u) | (m7 == c ? 0x3F800000u : 0u);
        accs[tt2 * 4 + 0] = __builtin_amdgcn_mfma_f32_16x16x32_bf16(oh.v, xf0, accs[tt2 * 4 + 0], 0, 0, 0);
        accs[tt2 * 4 + 1] = __builtin_amdgcn_mfma_f32_16x16x32_bf16(oh.v, xf1, accs[tt2 * 4 + 1], 0, 0, 0);
        accs[tt2 * 4 + 2] = __builtin_amdgcn_mfma_f32_16x16x32_bf16(oh.v, xf2, accs[tt2 * 4 + 2], 0, 0, 0);
        accs[tt2 * 4 + 3] = __builtin_amdgcn_mfma_f32_16x16x32_bf16(oh.v, xf3, accs[tt2 * 4 + 3], 0, 0, 0);
      }
    }
    __syncthreads();
  }

  // tail: exclusive centroid ownership -> direct global atomics (R13)
#pragma unroll
  for (int tt2 = 0; tt2 < 2; tt2++)
#pragma unroll
    for (int dt = 0; dt < 4; dt++)
#pragma unroll
      for (int r = 0; r < 4; r++)
        atomicAdd(&s_out[(size_t)(kbase + tt2 * 16 + grp * 4 + r) * DIM + dt * 16 + col],
                  accs[tt2 * 4 + dt][r]);
  for (int i = threadIdx.x; i < KC; i += 256) atomicAdd(&cnt_out[i], lc[i]);
}

// MFMA probs; denom inline per wave; nontemporal 256MB stores.
// BF=1: reads bf16 x from workspace (64MB instead of 128MB fp32, no cvt).
template <int BF>
__global__ __launch_bounds__(256, 2)
void k_probs(const float* __restrict__ x, const __bf16* __restrict__ xbp,
             const float* __restrict__ cent, const float* __restrict__ c2,
             float* __restrict__ out) {
  const int lane = threadIdx.x & 63;
  const int wid = threadIdx.x >> 6;
  const int col = lane & 15;
  const int grp = lane >> 4;

  bf16x8 afr[2][8];
  float c2g[32];
#pragma unroll
  for (int t = 0; t < 8; t++) {
    const float* cp = cent + (size_t)(t * 16 + col) * DIM;
#pragma unroll
    for (int ks = 0; ks < 2; ks++) {
      float4 f0 = *(const float4*)(cp + ks * 32 + grp * 8);
      float4 f1 = *(const float4*)(cp + ks * 32 + grp * 8 + 4);
      afr[ks][t] = cvt8(f0, f1);
    }
#pragma unroll
    for (int r = 0; r < 4; r++) c2g[t * 4 + r] = c2[t * 16 + grp * 4 + r];
  }

  float c2a = c2[lane], c2b = c2[64 + lane];
  float x2_0 = 0.f, dA = 0.f, dB = 0.f;
#pragma unroll 8
  for (int d = 0; d < DIM; d++) {
    float xv = x[d];
    x2_0 = fmaf(xv, xv, x2_0);
    dA = fmaf(xv, cent[(size_t)lane * DIM + d], dA);
    dB = fmaf(xv, cent[(size_t)(64 + lane) * DIM + d], dB);
  }
  float part = ((x2_0 + c2a) - 2.f * dA) + ((x2_0 + c2b) - 2.f * dB);
  float invd = 1.0f / wave_reduce_add(part);

  int w = blockIdx.x * 4 + wid;
  int nw = gridDim.x * 4;
  for (int t = w; t < NPTS / 16; t += nw) {
    int n0 = t * 16;
    bf16x8 xb0, xb1;
    float sq;
    if constexpr (BF) {
      const bf16x8* xr = (const bf16x8*)(xbp + (size_t)(n0 + col) * DIM + grp * 8);
      xb0 = xr[0]; xb1 = xr[4];
      sq = 0.f;
#pragma unroll
      for (int j = 0; j < 8; j++) {
        float u = (float)xb0[j], v = (float)xb1[j];
        sq += u * u + v * v;
      }
    } else {
      const float* xp = x + (size_t)(n0 + col) * DIM;
      float4 a0 = *(const float4*)(xp + grp * 8);
      float4 a1 = *(const float4*)(xp + grp * 8 + 4);
      float4 b0 = *(const float4*)(xp + 32 + grp * 8);
      float4 b1 = *(const float4*)(xp + 32 + grp * 8 + 4);
      xb0 = cvt8(a0, a1); xb1 = cvt8(b0, b1);
      sq = SSQ16(a0, a1, b0, b1);
    }
    sq += __shfl_xor(sq, 16, 64);
    sq += __shfl_xor(sq, 32, 64);

    f32x4 acc[8];
#pragma unroll
    for (int tt = 0; tt < 8; tt++) acc[tt] = (f32x4){0.f, 0.f, 0.f, 0.f};
#pragma unroll
    for (int tt = 0; tt < 8; tt++)
      acc[tt] = __builtin_amdgcn_mfma_f32_16x16x32_bf16(afr[0][tt], xb0, acc[tt], 0, 0, 0);
#pragma unroll
    for (int tt = 0; tt < 8; tt++)
      acc[tt] = __builtin_amdgcn_mfma_f32_16x16x32_bf16(afr[1][tt], xb1, acc[tt], 0, 0, 0);

    float* op = out + (size_t)(n0 + col) * KC + grp * 4;
#pragma unroll
    for (int tt = 0; tt < 8; tt++) {
      f32x4 q;
      q[0] = 1.f - ((sq + c2g[tt * 4 + 0]) - 2.f * acc[tt][0]) * invd;
      q[1] = 1.f - ((sq + c2g[tt * 4 + 1]) - 2.f * acc[tt][1]) * invd;
      q[2] = 1.f - ((sq + c2g[tt * 4 + 2]) - 2.f * acc[tt][2]) * invd;
      q[3] = 1.f - ((sq + c2g[tt * 4 + 3]) - 2.f * acc[tt][3]) * invd;
      __builtin_nontemporal_store(q, (f32x4*)(op + tt * 16));
    }
  }
}

extern "C" void kernel_launch(void* const* d_in, const int* in_sizes, int n_in,
                              void* d_out, int out_size, void* d_ws, size_t ws_size,
                              hipStream_t stream) {
  const float* x = (const float*)d_in[0];
  float* out = (float*)d_out;

  // ws: cent[8192] | c2[128] | S[10][8192] | CNT[10][128] | (optional) xb
  float* cent = (float*)d_ws;
  float* c2 = cent + KC * DIM;
  float* S = c2 + KC;
  float* CNT = S + KM_ITERS * KC * DIM;
  size_t xb_off_f = (size_t)(KC * DIM + KC + KM_ITERS * KC * DIM + KM_ITERS * KC);
  size_t need = xb_off_f * 4 + (size_t)NPTS * DIM * 2;
  bool ws_ok = ws_size >= need;
  __bf16* xb = ws_ok ? (__bf16*)((float*)d_ws + xb_off_f) : (__bf16*)d_out;

  k_initc<<<KC, DIM, 0, stream>>>(x, cent, c2, S, CNT);
  k_assign<1><<<512, 256, 0, stream>>>(x, xb, xb, cent, c2, nullptr, nullptr, S, CNT);
  for (int it = 1; it < KM_ITERS; it++) {
    k_assign<0><<<512, 256, 0, stream>>>(x, xb, xb, cent, c2,
                                         S + (it - 1) * KC * DIM, CNT + (it - 1) * KC,
                                         S + it * KC * DIM, CNT + it * KC);
  }
  k_update<<<KC, DIM, 0, stream>>>(S + 9 * KC * DIM, CNT + 9 * KC, cent, c2);
  if (ws_ok)
    k_probs<1><<<512, 256, 0, stream>>>(x, xb, cent, c2, out);
  else
    k_probs<0><<<512, 256, 0, stream>>>(x, xb, cent, c2, out);
}